// Round 8
// baseline (195.099 us; speedup 1.0000x reference)
//
#include <hip/hip_runtime.h>
#include <cstdint>

// Problem constants (fixed shape from setup_inputs): x [4,64,512,512] f32
#define BATCH 4
#define CH    64
#define HWSZ  262144           // 512*512 = 2^18
#define NLOC  (BATCH*HWSZ)     // 1048576 locations
#define NB_STATS (NLOC/256)    // 4096 blocks, 256 locations each
#define NORM_BLOCKS ((BATCH*CH*HWSZ)/4/256)  // 65536
#define EPS_BN 1e-5f

// ---------------------------------------------------------------------------
// Kernel 0: zero the 129 global accumulators (harness poisons d_ws once and
// never re-poisons; we must re-zero every call). 1 block, ~2 us.
// ---------------------------------------------------------------------------
__global__ void zero_kernel(float* __restrict__ g)
{
    if (threadIdx.x < 129) g[threadIdx.x] = 0.f;
}

// ---------------------------------------------------------------------------
// Kernel 1: fused mask + per-channel partial sums. Hot loop identical to R3
// (best measured). Tail changed: instead of writing [4096][64] partials to
// HBM (which forced an uncoalesced reduce kernel), each block atomicAdds its
// 64 channel-partials into global accumulators. One atomic per block per
// channel = 4096 adds/address, pipelined at the coherence point and
// overlapped with other blocks' memory phases (blocks finish staggered).
// Count is integer-valued f32 (< 2^24) => exact under any add order.
// ---------------------------------------------------------------------------
__global__ __launch_bounds__(256) void stats_kernel(
    const float* __restrict__ x,
    float* __restrict__ gsum,      // [64]
    float* __restrict__ gsumsq,    // [64]
    float* __restrict__ gcount,    // [1]
    unsigned char* __restrict__ maskout) // [NLOC]
{
    const int tid = threadIdx.x;
    const int q   = tid >> 6;          // wave id 0..3
    const int l   = tid & 63;          // lane id
    const int loc_base = blockIdx.x * 256;
    const int b       = loc_base >> 18;          // / HWSZ
    const int hw_base = loc_base & (HWSZ - 1);
    const int cbase   = q * 16;

    __shared__ unsigned int pmw[4][64];
    __shared__ float slds [64][67];   // stride 67 -> 2-way bank aliasing, free
    __shared__ float s2lds[64][67];
    __shared__ float comb[2][4][64];

    // 16 coalesced float4 loads per lane (one per owned channel)
    const float* xb = x + ((size_t)b * CH) * HWSZ + hw_base + l * 4;
    float4 val[16];
#pragma unroll
    for (int i = 0; i < 16; ++i)
        val[i] = *(const float4*)(xb + (size_t)(cbase + i) * HWSZ);

    // partial mask nibble for this wave's 16 channels (bit j = loc 4l+j)
    unsigned int bits = 0;
#pragma unroll
    for (int i = 0; i < 16; ++i) {
        bits |= (val[i].x > 0.f ? 1u : 0u)
              | (val[i].y > 0.f ? 2u : 0u)
              | (val[i].z > 0.f ? 4u : 0u)
              | (val[i].w > 0.f ? 8u : 0u);
    }

    // OR nibbles across the 4 waves (all waves cover the same 256 locations)
    pmw[q][l] = bits;
    __syncthreads();
    const unsigned int allbits =
        pmw[0][l] | pmw[1][l] | pmw[2][l] | pmw[3][l];

    const float m0 = (allbits & 1u) ? 1.f : 0.f;
    const float m1 = (allbits & 2u) ? 1.f : 0.f;
    const float m2 = (allbits & 4u) ? 1.f : 0.f;
    const float m3 = (allbits & 8u) ? 1.f : 0.f;

    // wave 0: write mask bytes + block valid-count (one atomic per block)
    if (q == 0) {
        unsigned int packed = (allbits & 1u ? 1u : 0u)
                            | (allbits & 2u ? 0x100u : 0u)
                            | (allbits & 4u ? 0x10000u : 0u)
                            | (allbits & 8u ? 0x1000000u : 0u);
        *(unsigned int*)(maskout + loc_base + l * 4) = packed;

        float cnt = (float)__popc(allbits & 0xFu);
#pragma unroll
        for (int off = 32; off; off >>= 1)
            cnt += __shfl_xor(cnt, off, 64);
        if (l == 0) atomicAdd(gcount, cnt);
    }

    // per-thread per-channel masked partials -> LDS transpose buffers
#pragma unroll
    for (int i = 0; i < 16; ++i) {
        const float t0 = val[i].x * m0;
        const float t1 = val[i].y * m1;
        const float t2 = val[i].z * m2;
        const float t3 = val[i].w * m3;
        slds [cbase + i][l] = (t0 + t1) + (t2 + t3);
        s2lds[cbase + i][l] = (t0 * val[i].x + t1 * val[i].y)
                            + (t2 * val[i].z + t3 * val[i].w);
    }
    __syncthreads();

    // read phase: thread handles (channel c, quarter part); wave-uniform part
    {
        const int c    = tid & 63;
        const int part = tid >> 6;
        float s = 0.f, s2 = 0.f;
#pragma unroll
        for (int j = 0; j < 16; ++j) {
            s  += slds [c][part * 16 + j];
            s2 += s2lds[c][part * 16 + j];
        }
        comb[0][part][c] = s;
        comb[1][part][c] = s2;
    }
    __syncthreads();

    if (tid < 64) {
        const float fs  = (comb[0][0][tid] + comb[0][1][tid])
                        + (comb[0][2][tid] + comb[0][3][tid]);
        const float fs2 = (comb[1][0][tid] + comb[1][1][tid])
                        + (comb[1][2][tid] + comb[1][3][tid]);
        atomicAdd(&gsum  [tid], fs);
        atomicAdd(&gsumsq[tid], fs2);
    }
}

// ---------------------------------------------------------------------------
// Kernel 2: normalize. Hot loop identical to R3. scale/shift computed INLINE
// from the global totals (wave-uniform broadcast loads + ~20 VALU cycles per
// block — replaces the uncoalesced reduce kernel and its launch gap).
// ---------------------------------------------------------------------------
__global__ __launch_bounds__(256) void norm_kernel(
    const float* __restrict__ x,
    const unsigned char* __restrict__ mask,
    const float* __restrict__ gsum,
    const float* __restrict__ gsumsq,
    const float* __restrict__ gcount,
    const float* __restrict__ weight,
    const float* __restrict__ bias,
    float* __restrict__ out)
{
    const size_t t = (size_t)blockIdx.x * 256 + threadIdx.x;
    const size_t e = t * 4;                       // NCHW flat element index
    const int c  = (int)((e >> 18) & 63);         // (e / HWSZ) % CH
    const int b  = (int)(e >> 24);                // / (CH*HWSZ)
    const int hw = (int)(e & (HWSZ - 1));
    const int loc = (b << 18) | hw;

    // inline scale/shift from global stats (uniform per block -> broadcast)
    const float cnt  = fmaxf(gcount[0], 1.f);
    const float mean = gsum[c] / cnt;
    const float var  = gsumsq[c] / cnt - mean * mean;
    const float inv  = rsqrtf(var + EPS_BN);
    const float sc   = inv * weight[c];
    const float sh   = bias[c] - mean * sc;

    const float4 v = *(const float4*)(x + e);
    const unsigned int mm = *(const unsigned int*)(mask + loc);

    float4 o;
    o.x = (mm & 0x000000FFu) ? fmaf(v.x, sc, sh) : v.x;
    o.y = (mm & 0x0000FF00u) ? fmaf(v.y, sc, sh) : v.y;
    o.z = (mm & 0x00FF0000u) ? fmaf(v.z, sc, sh) : v.z;
    o.w = (mm & 0xFF000000u) ? fmaf(v.w, sc, sh) : v.w;

    *(float4*)(out + e) = o;
}

// ---------------------------------------------------------------------------
extern "C" void kernel_launch(void* const* d_in, const int* in_sizes, int n_in,
                              void* d_out, int out_size, void* d_ws, size_t ws_size,
                              hipStream_t stream) {
    const float* x      = (const float*)d_in[0];
    const float* weight = (const float*)d_in[1];
    const float* bias   = (const float*)d_in[2];
    float* out = (float*)d_out;

    // workspace: gsum[64] | gsumsq[64] | gcount[1] | mask[NLOC bytes]
    float* gsum   = (float*)d_ws;
    float* gsumsq = gsum + 64;
    float* gcount = gsumsq + 64;
    unsigned char* mask = (unsigned char*)(gcount + 1);

    zero_kernel<<<1, 256, 0, stream>>>(gsum);
    stats_kernel<<<NB_STATS, 256, 0, stream>>>(x, gsum, gsumsq, gcount, mask);
    norm_kernel<<<NORM_BLOCKS, 256, 0, stream>>>(x, mask, gsum, gsumsq, gcount,
                                                 weight, bias, out);
}